// Round 1
// baseline (286.300 us; speedup 1.0000x reference)
//
#include <hip/hip_runtime.h>

#define NODES 100000
#define EDGES 1600000
#define BSH 8
#define NBUCK ((NODES + 255) >> BSH)   // 391
#define CHUNK 4096
#define LMAX 8192
#define MCHUNKS ((NODES + 31) / 32)    // 3125
// IN_F = HID_F = 128, OUT_F = 64

using bf16x8 = __attribute__((ext_vector_type(8))) short;
using f32x4  = __attribute__((ext_vector_type(4))) float;
using f32x2  = __attribute__((ext_vector_type(2))) float;

__device__ __forceinline__ unsigned short f2b(float f) {
    unsigned u = __builtin_bit_cast(unsigned, f);
    unsigned r = (u + 0x7FFFu + ((u >> 16) & 1u)) >> 16;
    return (unsigned short)r;
}

// ---- packed f32 helpers (CDNA VOP3P; dual-pump FP32) ----
__device__ __forceinline__ f32x2 pkadd(f32x2 a, f32x2 b) {
    f32x2 d;
    asm("v_pk_add_f32 %0, %1, %2" : "=v"(d) : "v"(a), "v"(b));
    return d;
}
__device__ __forceinline__ f32x2 pkfma(f32x2 a, f32x2 b, f32x2 c) {
    f32x2 d;
    asm("v_pk_fma_f32 %0, %1, %2, %3" : "=v"(d) : "v"(a), "v"(b), "v"(c));
    return d;
}
__device__ __forceinline__ unsigned cvt2bf(float lo, float hi) {
    unsigned r;
    asm("v_cvt_pk_bf16_f32 %0, %1, %2" : "=v"(r) : "v"(lo), "v"(hi));
    return r;
}

// unpack 8 fp8 (uint2) and accumulate into 4 packed-f32 accumulators
__device__ __forceinline__ void addpk8(f32x2* a, uint2 v) {
    a[0] = pkadd(a[0], __builtin_amdgcn_cvt_pk_f32_fp8((int)v.x, false));
    a[1] = pkadd(a[1], __builtin_amdgcn_cvt_pk_f32_fp8((int)v.x, true));
    a[2] = pkadd(a[2], __builtin_amdgcn_cvt_pk_f32_fp8((int)v.y, false));
    a[3] = pkadd(a[3], __builtin_amdgcn_cvt_pk_f32_fp8((int)v.y, true));
}

// ---------------- CSR build (no fine-grained global atomics) ----------------

__global__ __launch_bounds__(256) void bhist_kernel(const int* __restrict__ dst,
                                                    int* __restrict__ bucket_cnt) {
    __shared__ int lcnt[512];
    int t = threadIdx.x;
    lcnt[t] = 0; lcnt[t + 256] = 0;
    __syncthreads();
    int base = blockIdx.x * 16384;
    int n = EDGES - base;
    if (n > 16384) n = 16384;
    const int4* d4 = reinterpret_cast<const int4*>(dst + base);
    for (int i = t; i < (n >> 2); i += 256) {
        int4 d = d4[i];
        atomicAdd(&lcnt[d.x >> BSH], 1);
        atomicAdd(&lcnt[d.y >> BSH], 1);
        atomicAdd(&lcnt[d.z >> BSH], 1);
        atomicAdd(&lcnt[d.w >> BSH], 1);
    }
    for (int i = (n & ~3) + t; i < n; i += 256) atomicAdd(&lcnt[dst[base + i] >> BSH], 1);
    __syncthreads();
    if (lcnt[t]) atomicAdd(&bucket_cnt[t], lcnt[t]);
    if (lcnt[t + 256]) atomicAdd(&bucket_cnt[t + 256], lcnt[t + 256]);
}

__global__ void bscan_kernel(const int* __restrict__ bucket_cnt, int* __restrict__ bucket_off,
                             int* __restrict__ gcursor, int* __restrict__ row_ptr) {
    __shared__ int sh[512];
    int t = threadIdx.x;
    int v = (t < NBUCK) ? bucket_cnt[t] : 0;
    sh[t] = v;
    __syncthreads();
    for (int off = 1; off < 512; off <<= 1) {
        int x = (t >= off) ? sh[t - off] : 0;
        __syncthreads();
        sh[t] += x;
        __syncthreads();
    }
    int excl = sh[t] - v;
    if (t < NBUCK) { bucket_off[t] = excl; gcursor[t] = excl; }
    if (t == NBUCK) bucket_off[t] = EDGES;
    if (t == 0) row_ptr[NODES] = EDGES;
}

// Bin edges by coarse bucket; write packed (dst&255)<<24|src runs.
__global__ __launch_bounds__(256) void binscat_kernel(
    const int* __restrict__ src, const int* __restrict__ dst,
    int* __restrict__ gcursor, unsigned* __restrict__ pairs) {
    __shared__ int cnt[512];
    __shared__ int scn[512];
    __shared__ int gbs[512];
    __shared__ int cur[512];
    __shared__ uint2 stage[CHUNK];
    int t = threadIdx.x;
    int base = blockIdx.x * CHUNK;
    int n = EDGES - base;
    if (n > CHUNK) n = CHUNK;

    cnt[t] = 0; cnt[t + 256] = 0;
    __syncthreads();

    uint2 my[16];
#pragma unroll
    for (int i = 0; i < 16; ++i) {
        int idx = t + i * 256;
        if (idx < n) {
            int d = dst[base + idx];
            int s = src[base + idx];
            my[i] = make_uint2((unsigned)d, (unsigned)s);
            atomicAdd(&cnt[d >> BSH], 1);
        } else {
            my[i] = make_uint2(0xFFFFFFFFu, 0);
        }
    }
    __syncthreads();
    scn[t] = cnt[t]; scn[t + 256] = cnt[t + 256];
    __syncthreads();
    for (int off = 1; off < 512; off <<= 1) {
        int a0 = (t >= off) ? scn[t - off] : 0;
        int a1 = (t + 256 >= off) ? scn[t + 256 - off] : 0;
        __syncthreads();
        scn[t] += a0; scn[t + 256] += a1;
        __syncthreads();
    }
    cur[t] = scn[t] - cnt[t];
    cur[t + 256] = scn[t + 256] - cnt[t + 256];
    __syncthreads();
#pragma unroll
    for (int i = 0; i < 16; ++i) {
        if (my[i].x != 0xFFFFFFFFu) {
            int b = (int)(my[i].x >> BSH);
            int p = atomicAdd(&cur[b], 1);
            stage[p] = my[i];
        }
    }
    for (int b2 = t; b2 < 512; b2 += 256) {
        int c = cnt[b2];
        gbs[b2] = (c > 0 && b2 < NBUCK) ? atomicAdd(&gcursor[b2], c) : 0;
    }
    __syncthreads();
    for (int idx = t; idx < n; idx += 256) {
        uint2 p = stage[idx];
        int b = (int)(p.x >> BSH);
        int excl = scn[b] - cnt[b];
        pairs[gbs[b] + idx - excl] = ((p.x & 255u) << 24) | p.y;
    }
}

__global__ __launch_bounds__(256) void localsort_kernel(
    const unsigned* __restrict__ pairs, const int* __restrict__ bucket_off,
    int* __restrict__ row_ptr, int* __restrict__ src_sorted) {
    __shared__ int cnt[256];
    __shared__ int cur[256];
    __shared__ int stage[LMAX];
    int b = blockIdx.x;
    int t = threadIdx.x;
    int node0 = b << BSH;
    int pbeg = bucket_off[b], pend = bucket_off[b + 1];
    int n = pend - pbeg;
    cnt[t] = 0;
    __syncthreads();
    for (int e = pbeg + t; e < pend; e += 256)
        atomicAdd(&cnt[(int)(pairs[e] >> 24)], 1);
    __syncthreads();
    int v = cnt[t];
    cur[t] = v;
    __syncthreads();
    for (int off = 1; off < 256; off <<= 1) {
        int x = (t >= off) ? cur[t - off] : 0;
        __syncthreads();
        cur[t] += x;
        __syncthreads();
    }
    int excl = cur[t] - v;
    int node = node0 + t;
    if (node < NODES) row_ptr[node] = pbeg + excl;
    cur[t] = excl;
    __syncthreads();
    if (n <= LMAX) {
        for (int e = pbeg + t; e < pend; e += 256) {
            unsigned p = pairs[e];
            int pos = atomicAdd(&cur[(int)(p >> 24)], 1);
            stage[pos] = (int)(p & 0xFFFFFFu);
        }
        __syncthreads();
        for (int i = t; i < n; i += 256) src_sorted[pbeg + i] = stage[i];
    } else {
        for (int e = pbeg + t; e < pend; e += 256) {
            unsigned p = pairs[e];
            int pos = atomicAdd(&cur[(int)(p >> 24)], 1);
            src_sorted[pbeg + pos] = (int)(p & 0xFFFFFFu);
        }
    }
}

// ---------------- conversions (features->bf16+fp8, weights->bf16^T) ----------------

__global__ void conv_kernel(const float* __restrict__ in, unsigned short* __restrict__ outb,
                            unsigned char* __restrict__ outq, int n4,
                            const float* __restrict__ W1s, const float* __restrict__ W1n,
                            const float* __restrict__ W2s, const float* __restrict__ W2n,
                            unsigned short* __restrict__ Wt1s, unsigned short* __restrict__ Wt1n,
                            unsigned short* __restrict__ Wt2s, unsigned short* __restrict__ Wt2n) {
    int i = blockIdx.x * 256 + threadIdx.x;
    if (i < n4) {
        float4 v = reinterpret_cast<const float4*>(in)[i];
        uint2 o;
        o.x = (unsigned)f2b(v.x) | ((unsigned)f2b(v.y) << 16);
        o.y = (unsigned)f2b(v.z) | ((unsigned)f2b(v.w) << 16);
        reinterpret_cast<uint2*>(outb)[i] = o;
        int pk = __builtin_amdgcn_cvt_pk_fp8_f32(v.x, v.y, 0, false);
        pk = __builtin_amdgcn_cvt_pk_fp8_f32(v.z, v.w, pk, true);
        reinterpret_cast<unsigned*>(outq)[i] = (unsigned)pk;
    }
    if (i < 16384) {
        int k = i >> 7, n = i & 127;
        Wt1s[n * 128 + k] = f2b(W1s[i]);
        Wt1n[n * 128 + k] = f2b(W1n[i]);
    }
    if (i < 8192) {
        int k = i >> 6, n = i & 63;
        Wt2s[n * 128 + k] = f2b(W2s[i]);
        Wt2n[n * 128 + k] = f2b(W2n[i]);
    }
}

// ---------------- Mean aggregation, fp8 gather ----------------
// agg128: one wave/node; 16 lanes/row x 8B fp8 (8 feats), 4 groups.
// v2: unroll-4 edge pipeline (4 gathers in flight, latency paid once for
// mean-degree-16 nodes) + v_pk_add_f32 packed accumulation.

__global__ __launch_bounds__(256) void agg128_fp8(
    const unsigned char* __restrict__ xq, const int* __restrict__ row_ptr,
    const int* __restrict__ srcs, unsigned short* __restrict__ out) {
    int w = (blockIdx.x * 256 + threadIdx.x) >> 6;
    int lane = threadIdx.x & 63;
    if (w >= NODES) return;
    int g = lane >> 4;
    int sl = lane & 15;
    int beg = row_ptr[w], end = row_ptr[w + 1];

    f32x2 A0[4], A1[4];
#pragma unroll
    for (int i = 0; i < 4; ++i) { A0[i] = {0.f, 0.f}; A1[i] = {0.f, 0.f}; }

    const unsigned char* xs = xq + sl * 8;
    int e = beg + g;
    // main: 4 edges per group per iteration — all 4 index loads then all 4
    // row gathers issue before any convert (4 VMEM in flight).
    for (; e + 12 < end; e += 16) {
        int s0 = srcs[e];
        int s1 = srcs[e + 4];
        int s2 = srcs[e + 8];
        int s3 = srcs[e + 12];
        uint2 v0 = *reinterpret_cast<const uint2*>(xs + (size_t)s0 * 128);
        uint2 v1 = *reinterpret_cast<const uint2*>(xs + (size_t)s1 * 128);
        uint2 v2 = *reinterpret_cast<const uint2*>(xs + (size_t)s2 * 128);
        uint2 v3 = *reinterpret_cast<const uint2*>(xs + (size_t)s3 * 128);
        addpk8(A0, v0);
        addpk8(A1, v1);
        addpk8(A0, v2);
        addpk8(A1, v3);
    }
    // mid: 2-wide
    for (; e + 4 < end; e += 8) {
        int s0 = srcs[e];
        int s1 = srcs[e + 4];
        uint2 v0 = *reinterpret_cast<const uint2*>(xs + (size_t)s0 * 128);
        uint2 v1 = *reinterpret_cast<const uint2*>(xs + (size_t)s1 * 128);
        addpk8(A0, v0);
        addpk8(A1, v1);
    }
    if (e < end) {
        int s0 = srcs[e];
        uint2 v0 = *reinterpret_cast<const uint2*>(xs + (size_t)s0 * 128);
        addpk8(A0, v0);
    }

#pragma unroll
    for (int i = 0; i < 4; ++i) {
        f32x2 s = pkadd(A0[i], A1[i]);
        f32x2 t;
        t[0] = __shfl_xor(s[0], 16, 64);
        t[1] = __shfl_xor(s[1], 16, 64);
        s = pkadd(s, t);
        t[0] = __shfl_xor(s[0], 32, 64);
        t[1] = __shfl_xor(s[1], 32, 64);
        A0[i] = pkadd(s, t);
    }
    if (g == 0) {
        float inv = 1.0f / fmaxf((float)(end - beg), 1.0f);
        uint4 o;
        o.x = cvt2bf(A0[0][0] * inv, A0[0][1] * inv);
        o.y = cvt2bf(A0[1][0] * inv, A0[1][1] * inv);
        o.z = cvt2bf(A0[2][0] * inv, A0[2][1] * inv);
        o.w = cvt2bf(A0[3][0] * inv, A0[3][1] * inv);
        *reinterpret_cast<uint4*>(out + (size_t)w * 128 + sl * 8) = o;
    }
}

// agg64: one wave/node; 8 lanes/row x 8B fp8, 8 groups, unroll 2. out += mean.
// v2: v_pk_add_f32 accumulation + v_pk_fma_f32 epilogue.
__global__ __launch_bounds__(256) void agg64_add8(
    const unsigned char* __restrict__ xq, const int* __restrict__ row_ptr,
    const int* __restrict__ srcs, float* __restrict__ out) {
    int w = (blockIdx.x * 256 + threadIdx.x) >> 6;
    int lane = threadIdx.x & 63;
    if (w >= NODES) return;
    int g = lane >> 3;
    int sl = lane & 7;
    int beg = row_ptr[w], end = row_ptr[w + 1];

    f32x2 A0[4], A1[4];
#pragma unroll
    for (int i = 0; i < 4; ++i) { A0[i] = {0.f, 0.f}; A1[i] = {0.f, 0.f}; }

    const unsigned char* xs = xq + sl * 8;
    int e = beg + g;
    for (; e + 8 < end; e += 16) {
        int s0 = srcs[e];
        int s1 = srcs[e + 8];
        uint2 v0 = *reinterpret_cast<const uint2*>(xs + (size_t)s0 * 64);
        uint2 v1 = *reinterpret_cast<const uint2*>(xs + (size_t)s1 * 64);
        addpk8(A0, v0);
        addpk8(A1, v1);
    }
    if (e < end) {
        int s0 = srcs[e];
        uint2 v0 = *reinterpret_cast<const uint2*>(xs + (size_t)s0 * 64);
        addpk8(A0, v0);
    }
#pragma unroll
    for (int i = 0; i < 4; ++i) {
        f32x2 s = pkadd(A0[i], A1[i]);
        f32x2 t;
        t[0] = __shfl_xor(s[0], 8, 64);
        t[1] = __shfl_xor(s[1], 8, 64);
        s = pkadd(s, t);
        t[0] = __shfl_xor(s[0], 16, 64);
        t[1] = __shfl_xor(s[1], 16, 64);
        s = pkadd(s, t);
        t[0] = __shfl_xor(s[0], 32, 64);
        t[1] = __shfl_xor(s[1], 32, 64);
        A0[i] = pkadd(s, t);
    }
    if (g == 0) {
        float inv = 1.0f / fmaxf((float)(end - beg), 1.0f);
        f32x2 iv = {inv, inv};
        f32x2* op = reinterpret_cast<f32x2*>(out + (size_t)w * 64 + sl * 8);
        f32x2 r0 = op[0], r1 = op[1], r2 = op[2], r3 = op[3];
        op[0] = pkfma(A0[0], iv, r0);
        op[1] = pkfma(A0[1], iv, r1);
        op[2] = pkfma(A0[2], iv, r2);
        op[3] = pkfma(A0[3], iv, r3);
    }
}

// ---------------- Fused MLP: grid-stride + double-buffered LDS + A prefetch ----
// x1 = relu(feat@W1s + agg@W1n + b1) lives only in LDS; x1h8 = fp8(x1@W2n);
// outp = x1@W2s + b2. One barrier per chunk (buffer parity proves safety);
// next chunk's A fragments prefetched while phase2 runs.

__global__ __launch_bounds__(256, 2) void fused_mlp(
    const unsigned short* __restrict__ featb, const unsigned short* __restrict__ agg,
    const unsigned short* __restrict__ Wt1s, const unsigned short* __restrict__ Wt1n,
    const float* __restrict__ b1, const unsigned short* __restrict__ Wt2s,
    const unsigned short* __restrict__ Wt2n, const float* __restrict__ b2,
    unsigned char* __restrict__ x1h8, float* __restrict__ outp) {
    __shared__ __align__(16) unsigned short x1t[2][32 * 136];
    int wid = threadIdx.x >> 6, lane = threadIdx.x & 63;
    int l15 = lane & 15, quad = lane >> 4;

    // weight strips: W1 cols [wid*32, +32), W2 cols [wid*16, +16)
    bf16x8 B1s[2][4], B1n[2][4];
#pragma unroll
    for (int nt = 0; nt < 2; ++nt) {
        int col = wid * 32 + nt * 16 + l15;
#pragma unroll
        for (int k = 0; k < 4; ++k) {
            B1s[nt][k] = *reinterpret_cast<const bf16x8*>(Wt1s + (size_t)col * 128 + k * 32 + quad * 8);
            B1n[nt][k] = *reinterpret_cast<const bf16x8*>(Wt1n + (size_t)col * 128 + k * 32 + quad * 8);
        }
    }
    bf16x8 B2s[4], B2n[4];
    int col2 = wid * 16 + l15;
#pragma unroll
    for (int k = 0; k < 4; ++k) {
        B2s[k] = *reinterpret_cast<const bf16x8*>(Wt2s + (size_t)col2 * 128 + k * 32 + quad * 8);
        B2n[k] = *reinterpret_cast<const bf16x8*>(Wt2n + (size_t)col2 * 128 + k * 32 + quad * 8);
    }
    float bv1[2];
    bv1[0] = b1[wid * 32 + l15];
    bv1[1] = b1[wid * 32 + 16 + l15];
    float bv2 = b2[col2];

    auto loadA = [&](int cc, bf16x8 (&Afd)[2][4], bf16x8 (&Aad)[2][4]) {
#pragma unroll
        for (int rg = 0; rg < 2; ++rg) {
            int r = cc * 32 + rg * 16 + l15;
            if (r >= NODES) r = NODES - 1;
            const unsigned short* fp = featb + (size_t)r * 128 + quad * 8;
            const unsigned short* ap = agg + (size_t)r * 128 + quad * 8;
#pragma unroll
            for (int k = 0; k < 4; ++k) {
                Afd[rg][k] = *reinterpret_cast<const bf16x8*>(fp + k * 32);
                Aad[rg][k] = *reinterpret_cast<const bf16x8*>(ap + k * 32);
            }
        }
    };

    bf16x8 Af[2][4], Aa[2][4];
    int c = blockIdx.x;
    if (c < MCHUNKS) loadA(c, Af, Aa);
    int buf = 0;
    for (; c < MCHUNKS; c += gridDim.x) {
        int rbase = c * 32;
        int cn = c + (int)gridDim.x;

        // phase 1: consume Af/Aa
        f32x4 acc[2][2];
#pragma unroll
        for (int rg = 0; rg < 2; ++rg)
#pragma unroll
            for (int nt = 0; nt < 2; ++nt) acc[rg][nt] = {0.f, 0.f, 0.f, 0.f};
#pragma unroll
        for (int k = 0; k < 4; ++k)
#pragma unroll
            for (int nt = 0; nt < 2; ++nt)
#pragma unroll
                for (int rg = 0; rg < 2; ++rg) {
                    acc[rg][nt] = __builtin_amdgcn_mfma_f32_16x16x32_bf16(Af[rg][k], B1s[nt][k], acc[rg][nt], 0, 0, 0);
                    acc[rg][nt] = __builtin_amdgcn_mfma_f32_16x16x32_bf16(Aa[rg][k], B1n[nt][k], acc[rg][nt], 0, 0, 0);
                }

        // prefetch next chunk's A (overlaps LDS write + barrier + phase 2)
        bf16x8 Pf[2][4], Pa[2][4];
        if (cn < MCHUNKS) loadA(cn, Pf, Pa);

        // epilogue phase 1 -> LDS
#pragma unroll
        for (int nt = 0; nt < 2; ++nt)
#pragma unroll
            for (int rg = 0; rg < 2; ++rg)
#pragma unroll
                for (int rr = 0; rr < 4; ++rr) {
                    float v = fmaxf(acc[rg][nt][rr] + bv1[nt], 0.f);
                    x1t[buf][(rg * 16 + quad * 4 + rr) * 136 + wid * 32 + nt * 16 + l15] = f2b(v);
                }
        __syncthreads();

        // phase 2: layer-2 GEMMs from LDS x1 tile
        f32x4 acc2s[2], acc2n[2];
#pragma unroll
        for (int rg = 0; rg < 2; ++rg) { acc2s[rg] = {0.f, 0.f, 0.f, 0.f}; acc2n[rg] = {0.f, 0.f, 0.f, 0.f}; }
#pragma unroll
        for (int k = 0; k < 4; ++k)
#pragma unroll
            for (int rg = 0; rg < 2; ++rg) {
                bf16x8 a = *reinterpret_cast<const bf16x8*>(&x1t[buf][(rg * 16 + l15) * 136 + k * 32 + quad * 8]);
                acc2s[rg] = __builtin_amdgcn_mfma_f32_16x16x32_bf16(a, B2s[k], acc2s[rg], 0, 0, 0);
                acc2n[rg] = __builtin_amdgcn_mfma_f32_16x16x32_bf16(a, B2n[k], acc2n[rg], 0, 0, 0);
            }
#pragma unroll
        for (int rg = 0; rg < 2; ++rg)
#pragma unroll
            for (int rr = 0; rr < 4; ++rr) {
                int row = rbase + rg * 16 + quad * 4 + rr;
                if (row < NODES) {
                    float vn = acc2n[rg][rr];
                    int pk = __builtin_amdgcn_cvt_pk_fp8_f32(vn, vn, 0, false);
                    x1h8[(size_t)row * 64 + col2] = (unsigned char)(pk & 0xFF);
                    outp[(size_t)row * 64 + col2] = acc2s[rg][rr] + bv2;
                }
            }

        // rotate buffers / prefetched A
        buf ^= 1;
        if (cn < MCHUNKS) {
#pragma unroll
            for (int rg = 0; rg < 2; ++rg)
#pragma unroll
                for (int k = 0; k < 4; ++k) {
                    Af[rg][k] = Pf[rg][k];
                    Aa[rg][k] = Pa[rg][k];
                }
        }
    }
}

// ---------------- launch ----------------

extern "C" void kernel_launch(void* const* d_in, const int* in_sizes, int n_in,
                              void* d_out, int out_size, void* d_ws, size_t ws_size,
                              hipStream_t stream) {
    const float* features = (const float*)d_in[0];
    const int* esrc = (const int*)d_in[1];
    const int* edst = (const int*)d_in[2];
    const float* W1s = (const float*)d_in[3];
    const float* W1n = (const float*)d_in[4];
    const float* b1  = (const float*)d_in[5];
    const float* W2s = (const float*)d_in[6];
    const float* W2n = (const float*)d_in[7];
    const float* b2  = (const float*)d_in[8];
    float* out = (float*)d_out;

    char* ws = (char*)d_ws;
    size_t off = 0;
    auto alloc = [&](size_t bytes) {
        void* p = ws + off;
        off += (bytes + 255) & ~(size_t)255;
        return p;
    };
    int* bucket_cnt = (int*)alloc(512 * 4);
    int* bucket_off = (int*)alloc(512 * 4);
    int* gcursor    = (int*)alloc(512 * 4);
    int* row_ptr    = (int*)alloc((size_t)(NODES + 1) * 4);
    int* src_sorted = (int*)alloc((size_t)EDGES * 4);
    unsigned* pairs = (unsigned*)alloc((size_t)EDGES * 4);
    unsigned short* featb = (unsigned short*)alloc((size_t)NODES * 128 * 2);
    unsigned char*  feat8 = (unsigned char*)alloc((size_t)NODES * 128);
    unsigned short* agg1  = (unsigned short*)alloc((size_t)NODES * 128 * 2);
    unsigned char*  x1h8  = (unsigned char*)alloc((size_t)NODES * 64);
    unsigned short* Wt1s  = (unsigned short*)alloc(16384 * 2);
    unsigned short* Wt1n  = (unsigned short*)alloc(16384 * 2);
    unsigned short* Wt2s  = (unsigned short*)alloc(8192 * 2);
    unsigned short* Wt2n  = (unsigned short*)alloc(8192 * 2);

    // conversions (features -> bf16+fp8; weights -> bf16 transposed)
    conv_kernel<<<(NODES * 128 / 4 + 255) / 256, 256, 0, stream>>>(
        features, featb, feat8, NODES * 128 / 4, W1s, W1n, W2s, W2n, Wt1s, Wt1n, Wt2s, Wt2n);

    // CSR build: coarse hist -> bucket scan -> bucket bin -> per-bucket sort
    hipMemsetAsync(bucket_cnt, 0, 512 * 4, stream);
    bhist_kernel<<<(EDGES + 16383) / 16384, 256, 0, stream>>>(edst, bucket_cnt);
    bscan_kernel<<<1, 512, 0, stream>>>(bucket_cnt, bucket_off, gcursor, row_ptr);
    binscat_kernel<<<(EDGES + CHUNK - 1) / CHUNK, 256, 0, stream>>>(esrc, edst, gcursor, pairs);
    localsort_kernel<<<NBUCK, 256, 0, stream>>>(pairs, bucket_off, row_ptr, src_sorted);

    // layer 1 aggregation (fp8 gather -> bf16 agg matrix)
    agg128_fp8<<<(NODES * 64 + 255) / 256, 256, 0, stream>>>(feat8, row_ptr, src_sorted, agg1);

    // fused MLP: x1 in LDS; writes x1h fp8 + out (self part + bias)
    fused_mlp<<<1024, 256, 0, stream>>>(featb, agg1, Wt1s, Wt1n, b1, Wt2s, Wt2n, b2, x1h8, out);

    // out += mean-neigh(x1h)
    agg64_add8<<<(NODES * 64 + 255) / 256, 256, 0, stream>>>(x1h8, row_ptr, src_sorted, out);
}

// Round 3
// 259.182 us; speedup vs baseline: 1.1046x; 1.1046x over previous
//
#include <hip/hip_runtime.h>

#define NODES 100000
#define EDGES 1600000
#define BSH 8
#define NBUCK ((NODES + 255) >> BSH)   // 391
#define CHUNK 4096
#define LMAX 8192
#define MCHUNKS ((NODES + 31) / 32)    // 3125
#define CONVB 12500                    // blocks for conv part of conv_hist
// IN_F = HID_F = 128, OUT_F = 64

using bf16x8 = __attribute__((ext_vector_type(8))) short;
using f32x4  = __attribute__((ext_vector_type(4))) float;
using f32x2  = __attribute__((ext_vector_type(2))) float;

__device__ __forceinline__ unsigned short f2b(float f) {
    unsigned u = __builtin_bit_cast(unsigned, f);
    unsigned r = (u + 0x7FFFu + ((u >> 16) & 1u)) >> 16;
    return (unsigned short)r;
}

// ---- packed f32 helpers (CDNA VOP3P; dual-pump FP32) ----
__device__ __forceinline__ f32x2 pkadd(f32x2 a, f32x2 b) {
    f32x2 d;
    asm("v_pk_add_f32 %0, %1, %2" : "=v"(d) : "v"(a), "v"(b));
    return d;
}
__device__ __forceinline__ f32x2 pkfma(f32x2 a, f32x2 b, f32x2 c) {
    f32x2 d;
    asm("v_pk_fma_f32 %0, %1, %2, %3" : "=v"(d) : "v"(a), "v"(b), "v"(c));
    return d;
}
__device__ __forceinline__ unsigned cvt2bf(float lo, float hi) {
    unsigned r;
    asm("v_cvt_pk_bf16_f32 %0, %1, %2" : "=v"(r) : "v"(lo), "v"(hi));
    return r;
}

// unpack 8 fp8 (uint2) and accumulate into 4 packed-f32 accumulators
__device__ __forceinline__ void addpk8(f32x2* a, uint2 v) {
    a[0] = pkadd(a[0], __builtin_amdgcn_cvt_pk_f32_fp8((int)v.x, false));
    a[1] = pkadd(a[1], __builtin_amdgcn_cvt_pk_f32_fp8((int)v.x, true));
    a[2] = pkadd(a[2], __builtin_amdgcn_cvt_pk_f32_fp8((int)v.y, false));
    a[3] = pkadd(a[3], __builtin_amdgcn_cvt_pk_f32_fp8((int)v.y, true));
}

// ---------------- fused conversions + coarse histogram ----------------
// blocks [0, CONVB): features->bf16+fp8, weights->bf16^T
// blocks [CONVB, ...): bhist over dst

__global__ __launch_bounds__(256) void conv_hist(
    const float* __restrict__ in, unsigned short* __restrict__ outb,
    unsigned char* __restrict__ outq, int n4,
    const float* __restrict__ W1s, const float* __restrict__ W1n,
    const float* __restrict__ W2s, const float* __restrict__ W2n,
    unsigned short* __restrict__ Wt1s, unsigned short* __restrict__ Wt1n,
    unsigned short* __restrict__ Wt2s, unsigned short* __restrict__ Wt2n,
    const int* __restrict__ dst, int* __restrict__ bucket_cnt) {
    int t = threadIdx.x;
    if (blockIdx.x < CONVB) {
        int i = blockIdx.x * 256 + t;
        if (i < n4) {
            float4 v = reinterpret_cast<const float4*>(in)[i];
            uint2 o;
            o.x = (unsigned)f2b(v.x) | ((unsigned)f2b(v.y) << 16);
            o.y = (unsigned)f2b(v.z) | ((unsigned)f2b(v.w) << 16);
            reinterpret_cast<uint2*>(outb)[i] = o;
            int pk = __builtin_amdgcn_cvt_pk_fp8_f32(v.x, v.y, 0, false);
            pk = __builtin_amdgcn_cvt_pk_fp8_f32(v.z, v.w, pk, true);
            reinterpret_cast<unsigned*>(outq)[i] = (unsigned)pk;
        }
        if (i < 16384) {
            int k = i >> 7, n = i & 127;
            Wt1s[n * 128 + k] = f2b(W1s[i]);
            Wt1n[n * 128 + k] = f2b(W1n[i]);
        }
        if (i < 8192) {
            int k = i >> 6, n = i & 63;
            Wt2s[n * 128 + k] = f2b(W2s[i]);
            Wt2n[n * 128 + k] = f2b(W2n[i]);
        }
        return;
    }
    // ---- bhist part ----
    __shared__ int lcnt[512];
    lcnt[t] = 0; lcnt[t + 256] = 0;
    __syncthreads();
    int base = (blockIdx.x - CONVB) * 16384;
    int n = EDGES - base;
    if (n > 16384) n = 16384;
    const int4* d4 = reinterpret_cast<const int4*>(dst + base);
    for (int i = t; i < (n >> 2); i += 256) {
        int4 d = d4[i];
        atomicAdd(&lcnt[d.x >> BSH], 1);
        atomicAdd(&lcnt[d.y >> BSH], 1);
        atomicAdd(&lcnt[d.z >> BSH], 1);
        atomicAdd(&lcnt[d.w >> BSH], 1);
    }
    for (int i = (n & ~3) + t; i < n; i += 256) atomicAdd(&lcnt[dst[base + i] >> BSH], 1);
    __syncthreads();
    if (lcnt[t]) atomicAdd(&bucket_cnt[t], lcnt[t]);
    if (lcnt[t + 256]) atomicAdd(&bucket_cnt[t + 256], lcnt[t + 256]);
}

__global__ void bscan_kernel(const int* __restrict__ bucket_cnt, int* __restrict__ bucket_off,
                             int* __restrict__ gcursor, int* __restrict__ row_ptr) {
    __shared__ int sh[512];
    int t = threadIdx.x;
    int v = (t < NBUCK) ? bucket_cnt[t] : 0;
    sh[t] = v;
    __syncthreads();
    for (int off = 1; off < 512; off <<= 1) {
        int x = (t >= off) ? sh[t - off] : 0;
        __syncthreads();
        sh[t] += x;
        __syncthreads();
    }
    int excl = sh[t] - v;
    if (t < NBUCK) { bucket_off[t] = excl; gcursor[t] = excl; }
    if (t == NBUCK) bucket_off[t] = EDGES;
    if (t == 0) row_ptr[NODES] = EDGES;
}

// Bin edges by coarse bucket; write packed (dst&255)<<24|src runs.
__global__ __launch_bounds__(256) void binscat_kernel(
    const int* __restrict__ src, const int* __restrict__ dst,
    int* __restrict__ gcursor, unsigned* __restrict__ pairs) {
    __shared__ int cnt[512];
    __shared__ int scn[512];
    __shared__ int gbs[512];
    __shared__ int cur[512];
    __shared__ uint2 stage[CHUNK];
    int t = threadIdx.x;
    int base = blockIdx.x * CHUNK;
    int n = EDGES - base;
    if (n > CHUNK) n = CHUNK;

    cnt[t] = 0; cnt[t + 256] = 0;
    __syncthreads();

    uint2 my[16];
#pragma unroll
    for (int i = 0; i < 16; ++i) {
        int idx = t + i * 256;
        if (idx < n) {
            int d = dst[base + idx];
            int s = src[base + idx];
            my[i] = make_uint2((unsigned)d, (unsigned)s);
            atomicAdd(&cnt[d >> BSH], 1);
        } else {
            my[i] = make_uint2(0xFFFFFFFFu, 0);
        }
    }
    __syncthreads();
    scn[t] = cnt[t]; scn[t + 256] = cnt[t + 256];
    __syncthreads();
    for (int off = 1; off < 512; off <<= 1) {
        int a0 = (t >= off) ? scn[t - off] : 0;
        int a1 = (t + 256 >= off) ? scn[t + 256 - off] : 0;
        __syncthreads();
        scn[t] += a0; scn[t + 256] += a1;
        __syncthreads();
    }
    cur[t] = scn[t] - cnt[t];
    cur[t + 256] = scn[t + 256] - cnt[t + 256];
    __syncthreads();
#pragma unroll
    for (int i = 0; i < 16; ++i) {
        if (my[i].x != 0xFFFFFFFFu) {
            int b = (int)(my[i].x >> BSH);
            int p = atomicAdd(&cur[b], 1);
            stage[p] = my[i];
        }
    }
    for (int b2 = t; b2 < 512; b2 += 256) {
        int c = cnt[b2];
        gbs[b2] = (c > 0 && b2 < NBUCK) ? atomicAdd(&gcursor[b2], c) : 0;
    }
    __syncthreads();
    for (int idx = t; idx < n; idx += 256) {
        uint2 p = stage[idx];
        int b = (int)(p.x >> BSH);
        int excl = scn[b] - cnt[b];
        pairs[gbs[b] + idx - excl] = ((p.x & 255u) << 24) | p.y;
    }
}

__global__ __launch_bounds__(256) void localsort_kernel(
    const unsigned* __restrict__ pairs, const int* __restrict__ bucket_off,
    int* __restrict__ row_ptr, int* __restrict__ src_sorted) {
    __shared__ int cnt[256];
    __shared__ int cur[256];
    __shared__ int stage[LMAX];
    int b = blockIdx.x;
    int t = threadIdx.x;
    int node0 = b << BSH;
    int pbeg = bucket_off[b], pend = bucket_off[b + 1];
    int n = pend - pbeg;
    cnt[t] = 0;
    __syncthreads();
    for (int e = pbeg + t; e < pend; e += 256)
        atomicAdd(&cnt[(int)(pairs[e] >> 24)], 1);
    __syncthreads();
    int v = cnt[t];
    cur[t] = v;
    __syncthreads();
    for (int off = 1; off < 256; off <<= 1) {
        int x = (t >= off) ? cur[t - off] : 0;
        __syncthreads();
        cur[t] += x;
        __syncthreads();
    }
    int excl = cur[t] - v;
    int node = node0 + t;
    if (node < NODES) row_ptr[node] = pbeg + excl;
    cur[t] = excl;
    __syncthreads();
    if (n <= LMAX) {
        for (int e = pbeg + t; e < pend; e += 256) {
            unsigned p = pairs[e];
            int pos = atomicAdd(&cur[(int)(p >> 24)], 1);
            stage[pos] = (int)(p & 0xFFFFFFu);
        }
        __syncthreads();
        for (int i = t; i < n; i += 256) src_sorted[pbeg + i] = stage[i];
    } else {
        for (int e = pbeg + t; e < pend; e += 256) {
            unsigned p = pairs[e];
            int pos = atomicAdd(&cur[(int)(p >> 24)], 1);
            src_sorted[pbeg + pos] = (int)(p & 0xFFFFFFu);
        }
    }
}

// ---------------- Mean aggregation, fp8 gather ----------------
// v3: group-per-node. 16-lane group owns one node (4 nodes/wave).
// One coalesced 16-wide srcs load per chunk; shfl-broadcast indices;
// all 16 row-gathers issued back-to-back (16 outstanding misses/group).
// Out-of-degree slots gather the all-zero pad row (index NODES): no
// masking in the inner loop. No cross-group reduce; all 64 lanes write.

__global__ __launch_bounds__(256) void agg128_fp8(
    const unsigned char* __restrict__ xq, const int* __restrict__ row_ptr,
    const int* __restrict__ srcs, unsigned short* __restrict__ out) {
    int wave = (blockIdx.x * 256 + threadIdx.x) >> 6;
    int lane = threadIdx.x & 63;
    int sl = lane & 15;
    int n = wave * 4 + (lane >> 4);
    if (n >= NODES) return;
    int beg = row_ptr[n], end = row_ptr[n + 1];
    int gb = lane & 48;  // group base lane (g*16)

    f32x2 A0[4], A1[4];
#pragma unroll
    for (int i = 0; i < 4; ++i) { A0[i] = {0.f, 0.f}; A1[i] = {0.f, 0.f}; }

    const unsigned char* xs = xq + sl * 8;
    for (int base = beg; base < end; base += 16) {
        int idx = base + sl;
        int sv = (idx < end) ? srcs[idx] : NODES;  // NODES = zero pad row
        uint2 vv[8], ww[8];
#pragma unroll
        for (int j = 0; j < 8; ++j) {
            int s = __shfl(sv, gb + j, 64);
            vv[j] = *reinterpret_cast<const uint2*>(xs + (size_t)s * 128);
        }
#pragma unroll
        for (int j = 0; j < 8; ++j) {
            int s = __shfl(sv, gb + 8 + j, 64);
            ww[j] = *reinterpret_cast<const uint2*>(xs + (size_t)s * 128);
        }
#pragma unroll
        for (int j = 0; j < 8; ++j) addpk8((j & 1) ? A1 : A0, vv[j]);
#pragma unroll
        for (int j = 0; j < 8; ++j) addpk8((j & 1) ? A0 : A1, ww[j]);
    }

    float inv = 1.0f / fmaxf((float)(end - beg), 1.0f);
    f32x2 iv = {inv, inv};
    f32x2 z = {0.f, 0.f};
    f32x2 r0 = pkfma(pkadd(A0[0], A1[0]), iv, z);
    f32x2 r1 = pkfma(pkadd(A0[1], A1[1]), iv, z);
    f32x2 r2 = pkfma(pkadd(A0[2], A1[2]), iv, z);
    f32x2 r3 = pkfma(pkadd(A0[3], A1[3]), iv, z);
    uint4 o;
    o.x = cvt2bf(r0[0], r0[1]);
    o.y = cvt2bf(r1[0], r1[1]);
    o.z = cvt2bf(r2[0], r2[1]);
    o.w = cvt2bf(r3[0], r3[1]);
    *reinterpret_cast<uint4*>(out + (size_t)n * 128 + sl * 8) = o;
}

// agg64: group-per-node, 8-lane groups (8 nodes/wave). Same zero-row trick.
__global__ __launch_bounds__(256) void agg64_add8(
    const unsigned char* __restrict__ xq, const int* __restrict__ row_ptr,
    const int* __restrict__ srcs, float* __restrict__ out) {
    int wave = (blockIdx.x * 256 + threadIdx.x) >> 6;
    int lane = threadIdx.x & 63;
    int sl = lane & 7;
    int n = wave * 8 + (lane >> 3);
    if (n >= NODES) return;
    int beg = row_ptr[n], end = row_ptr[n + 1];
    int gb = lane & 56;  // group base lane (g*8)

    f32x2 A0[4], A1[4];
#pragma unroll
    for (int i = 0; i < 4; ++i) { A0[i] = {0.f, 0.f}; A1[i] = {0.f, 0.f}; }

    const unsigned char* xs = xq + sl * 8;
    for (int base = beg; base < end; base += 8) {
        int idx = base + sl;
        int sv = (idx < end) ? srcs[idx] : NODES;  // zero pad row
        uint2 vv[8];
#pragma unroll
        for (int j = 0; j < 8; ++j) {
            int s = __shfl(sv, gb + j, 64);
            vv[j] = *reinterpret_cast<const uint2*>(xs + (size_t)s * 64);
        }
#pragma unroll
        for (int j = 0; j < 8; ++j) addpk8((j & 1) ? A1 : A0, vv[j]);
    }

    float inv = 1.0f / fmaxf((float)(end - beg), 1.0f);
    f32x2 iv = {inv, inv};
    float* op = out + (size_t)n * 64 + sl * 8;
    f32x2 r0 = *reinterpret_cast<f32x2*>(op);
    f32x2 r1 = *reinterpret_cast<f32x2*>(op + 2);
    f32x2 r2 = *reinterpret_cast<f32x2*>(op + 4);
    f32x2 r3 = *reinterpret_cast<f32x2*>(op + 6);
    r0 = pkfma(pkadd(A0[0], A1[0]), iv, r0);
    r1 = pkfma(pkadd(A0[1], A1[1]), iv, r1);
    r2 = pkfma(pkadd(A0[2], A1[2]), iv, r2);
    r3 = pkfma(pkadd(A0[3], A1[3]), iv, r3);
    *reinterpret_cast<f32x2*>(op) = r0;
    *reinterpret_cast<f32x2*>(op + 2) = r1;
    *reinterpret_cast<f32x2*>(op + 4) = r2;
    *reinterpret_cast<f32x2*>(op + 6) = r3;
}

// ---------------- Fused MLP: grid-stride + double-buffered LDS + A prefetch ----

__global__ __launch_bounds__(256, 2) void fused_mlp(
    const unsigned short* __restrict__ featb, const unsigned short* __restrict__ agg,
    const unsigned short* __restrict__ Wt1s, const unsigned short* __restrict__ Wt1n,
    const float* __restrict__ b1, const unsigned short* __restrict__ Wt2s,
    const unsigned short* __restrict__ Wt2n, const float* __restrict__ b2,
    unsigned char* __restrict__ x1h8, float* __restrict__ outp) {
    __shared__ __align__(16) unsigned short x1t[2][32 * 136];
    int wid = threadIdx.x >> 6, lane = threadIdx.x & 63;
    int l15 = lane & 15, quad = lane >> 4;

    bf16x8 B1s[2][4], B1n[2][4];
#pragma unroll
    for (int nt = 0; nt < 2; ++nt) {
        int col = wid * 32 + nt * 16 + l15;
#pragma unroll
        for (int k = 0; k < 4; ++k) {
            B1s[nt][k] = *reinterpret_cast<const bf16x8*>(Wt1s + (size_t)col * 128 + k * 32 + quad * 8);
            B1n[nt][k] = *reinterpret_cast<const bf16x8*>(Wt1n + (size_t)col * 128 + k * 32 + quad * 8);
        }
    }
    bf16x8 B2s[4], B2n[4];
    int col2 = wid * 16 + l15;
#pragma unroll
    for (int k = 0; k < 4; ++k) {
        B2s[k] = *reinterpret_cast<const bf16x8*>(Wt2s + (size_t)col2 * 128 + k * 32 + quad * 8);
        B2n[k] = *reinterpret_cast<const bf16x8*>(Wt2n + (size_t)col2 * 128 + k * 32 + quad * 8);
    }
    float bv1[2];
    bv1[0] = b1[wid * 32 + l15];
    bv1[1] = b1[wid * 32 + 16 + l15];
    float bv2 = b2[col2];

    auto loadA = [&](int cc, bf16x8 (&Afd)[2][4], bf16x8 (&Aad)[2][4]) {
#pragma unroll
        for (int rg = 0; rg < 2; ++rg) {
            int r = cc * 32 + rg * 16 + l15;
            if (r >= NODES) r = NODES - 1;
            const unsigned short* fp = featb + (size_t)r * 128 + quad * 8;
            const unsigned short* ap = agg + (size_t)r * 128 + quad * 8;
#pragma unroll
            for (int k = 0; k < 4; ++k) {
                Afd[rg][k] = *reinterpret_cast<const bf16x8*>(fp + k * 32);
                Aad[rg][k] = *reinterpret_cast<const bf16x8*>(ap + k * 32);
            }
        }
    };

    bf16x8 Af[2][4], Aa[2][4];
    int c = blockIdx.x;
    if (c < MCHUNKS) loadA(c, Af, Aa);
    int buf = 0;
    for (; c < MCHUNKS; c += gridDim.x) {
        int rbase = c * 32;
        int cn = c + (int)gridDim.x;

        f32x4 acc[2][2];
#pragma unroll
        for (int rg = 0; rg < 2; ++rg)
#pragma unroll
            for (int nt = 0; nt < 2; ++nt) acc[rg][nt] = {0.f, 0.f, 0.f, 0.f};
#pragma unroll
        for (int k = 0; k < 4; ++k)
#pragma unroll
            for (int nt = 0; nt < 2; ++nt)
#pragma unroll
                for (int rg = 0; rg < 2; ++rg) {
                    acc[rg][nt] = __builtin_amdgcn_mfma_f32_16x16x32_bf16(Af[rg][k], B1s[nt][k], acc[rg][nt], 0, 0, 0);
                    acc[rg][nt] = __builtin_amdgcn_mfma_f32_16x16x32_bf16(Aa[rg][k], B1n[nt][k], acc[rg][nt], 0, 0, 0);
                }

        bf16x8 Pf[2][4], Pa[2][4];
        if (cn < MCHUNKS) loadA(cn, Pf, Pa);

#pragma unroll
        for (int nt = 0; nt < 2; ++nt)
#pragma unroll
            for (int rg = 0; rg < 2; ++rg)
#pragma unroll
                for (int rr = 0; rr < 4; ++rr) {
                    float v = fmaxf(acc[rg][nt][rr] + bv1[nt], 0.f);
                    x1t[buf][(rg * 16 + quad * 4 + rr) * 136 + wid * 32 + nt * 16 + l15] = f2b(v);
                }
        __syncthreads();

        f32x4 acc2s[2], acc2n[2];
#pragma unroll
        for (int rg = 0; rg < 2; ++rg) { acc2s[rg] = {0.f, 0.f, 0.f, 0.f}; acc2n[rg] = {0.f, 0.f, 0.f, 0.f}; }
#pragma unroll
        for (int k = 0; k < 4; ++k)
#pragma unroll
            for (int rg = 0; rg < 2; ++rg) {
                bf16x8 a = *reinterpret_cast<const bf16x8*>(&x1t[buf][(rg * 16 + l15) * 136 + k * 32 + quad * 8]);
                acc2s[rg] = __builtin_amdgcn_mfma_f32_16x16x32_bf16(a, B2s[k], acc2s[rg], 0, 0, 0);
                acc2n[rg] = __builtin_amdgcn_mfma_f32_16x16x32_bf16(a, B2n[k], acc2n[rg], 0, 0, 0);
            }
#pragma unroll
        for (int rg = 0; rg < 2; ++rg)
#pragma unroll
            for (int rr = 0; rr < 4; ++rr) {
                int row = rbase + rg * 16 + quad * 4 + rr;
                if (row < NODES) {
                    float vn = acc2n[rg][rr];
                    int pk = __builtin_amdgcn_cvt_pk_fp8_f32(vn, vn, 0, false);
                    x1h8[(size_t)row * 64 + col2] = (unsigned char)(pk & 0xFF);
                    outp[(size_t)row * 64 + col2] = acc2s[rg][rr] + bv2;
                }
            }

        buf ^= 1;
        if (cn < MCHUNKS) {
#pragma unroll
            for (int rg = 0; rg < 2; ++rg)
#pragma unroll
                for (int k = 0; k < 4; ++k) {
                    Af[rg][k] = Pf[rg][k];
                    Aa[rg][k] = Pa[rg][k];
                }
        }
    }
}

// ---------------- launch ----------------

extern "C" void kernel_launch(void* const* d_in, const int* in_sizes, int n_in,
                              void* d_out, int out_size, void* d_ws, size_t ws_size,
                              hipStream_t stream) {
    const float* features = (const float*)d_in[0];
    const int* esrc = (const int*)d_in[1];
    const int* edst = (const int*)d_in[2];
    const float* W1s = (const float*)d_in[3];
    const float* W1n = (const float*)d_in[4];
    const float* b1  = (const float*)d_in[5];
    const float* W2s = (const float*)d_in[6];
    const float* W2n = (const float*)d_in[7];
    const float* b2  = (const float*)d_in[8];
    float* out = (float*)d_out;

    char* ws = (char*)d_ws;
    size_t off = 0;
    auto alloc = [&](size_t bytes) {
        void* p = ws + off;
        off += (bytes + 255) & ~(size_t)255;
        return p;
    };
    int* bucket_cnt = (int*)alloc(512 * 4);
    int* bucket_off = (int*)alloc(512 * 4);
    int* gcursor    = (int*)alloc(512 * 4);
    int* row_ptr    = (int*)alloc((size_t)(NODES + 1) * 4);
    int* src_sorted = (int*)alloc((size_t)EDGES * 4);
    unsigned* pairs = (unsigned*)alloc((size_t)EDGES * 4);
    unsigned short* featb = (unsigned short*)alloc((size_t)NODES * 128 * 2);
    unsigned char*  feat8 = (unsigned char*)alloc((size_t)(NODES + 1) * 128);  // +zero pad row
    unsigned short* agg1  = (unsigned short*)alloc((size_t)NODES * 128 * 2);
    unsigned char*  x1h8  = (unsigned char*)alloc((size_t)(NODES + 1) * 64);   // +zero pad row
    unsigned short* Wt1s  = (unsigned short*)alloc(16384 * 2);
    unsigned short* Wt1n  = (unsigned short*)alloc(16384 * 2);
    unsigned short* Wt2s  = (unsigned short*)alloc(8192 * 2);
    unsigned short* Wt2n  = (unsigned short*)alloc(8192 * 2);

    // zero pad rows + bucket counters
    hipMemsetAsync(bucket_cnt, 0, 512 * 4, stream);
    hipMemsetAsync(feat8 + (size_t)NODES * 128, 0, 128, stream);
    hipMemsetAsync(x1h8 + (size_t)NODES * 64, 0, 64, stream);

    // fused conversions + coarse histogram
    conv_hist<<<CONVB + (EDGES + 16383) / 16384, 256, 0, stream>>>(
        features, featb, feat8, NODES * 128 / 4, W1s, W1n, W2s, W2n,
        Wt1s, Wt1n, Wt2s, Wt2n, edst, bucket_cnt);

    bscan_kernel<<<1, 512, 0, stream>>>(bucket_cnt, bucket_off, gcursor, row_ptr);
    binscat_kernel<<<(EDGES + CHUNK - 1) / CHUNK, 256, 0, stream>>>(esrc, edst, gcursor, pairs);
    localsort_kernel<<<NBUCK, 256, 0, stream>>>(pairs, bucket_off, row_ptr, src_sorted);

    // layer 1 aggregation (fp8 gather -> bf16 agg matrix); 4 nodes/wave
    agg128_fp8<<<(NODES / 4 * 64 + 255) / 256, 256, 0, stream>>>(feat8, row_ptr, src_sorted, agg1);

    // fused MLP
    fused_mlp<<<1024, 256, 0, stream>>>(featb, agg1, Wt1s, Wt1n, b1, Wt2s, Wt2n, b2, x1h8, out);

    // out += mean-neigh(x1h); 8 nodes/wave
    agg64_add8<<<(NODES / 8 * 64 + 255) / 256, 256, 0, stream>>>(x1h8, row_ptr, src_sorted, out);
}